// Round 1
// baseline (562.726 us; speedup 1.0000x reference)
//
#include <hip/hip_runtime.h>

// Problem constants
#define NB    133
#define BATCH 256
#define HEADS 8
#define CDIM  128
#define DDIM  1024
#define MROWS (BATCH * NB)     // 34048 = 266 * 128 (exact!)
#define NDIM  (HEADS * CDIM)   // 1024

typedef __bf16 bf16_t;
typedef bf16_t bf16x8 __attribute__((ext_vector_type(8)));
typedef float  f32x4  __attribute__((ext_vector_type(4)));

__device__ __forceinline__ unsigned short f2bf(float f) {
  unsigned u = __float_as_uint(f);
  u += 0x7fffu + ((u >> 16) & 1u);   // RNE, non-NaN inputs
  return (unsigned short)(u >> 16);
}
__device__ __forceinline__ float bf2f(unsigned short s) {
  return __uint_as_float(((unsigned)s) << 16);
}
__device__ __forceinline__ void load_lds16(const void* g, void* l) {
  __builtin_amdgcn_global_load_lds(
      (__attribute__((address_space(1))) void*)(g),
      (__attribute__((address_space(3))) void*)(l), 16, 0, 0);
}

// ---------------- fp32 -> bf16 convert (8 elems/thread) ----------------
__global__ __launch_bounds__(256) void cvt_kernel(const float* __restrict__ src,
                                                  unsigned short* __restrict__ dst,
                                                  int n8) {
  int i = blockIdx.x * 256 + threadIdx.x;
  if (i >= n8) return;
  const float4* s4 = (const float4*)src;
  float4 a = s4[(size_t)i * 2];
  float4 b = s4[(size_t)i * 2 + 1];
  union { unsigned short u[8]; uint4 v; } p;
  p.u[0] = f2bf(a.x); p.u[1] = f2bf(a.y); p.u[2] = f2bf(a.z); p.u[3] = f2bf(a.w);
  p.u[4] = f2bf(b.x); p.u[5] = f2bf(b.y); p.u[6] = f2bf(b.z); p.u[7] = f2bf(b.w);
  ((uint4*)dst)[i] = p.v;
}

// ---------------- GEMM: g = x @ W^T (m97 structure) ----------------
// A = xb [34048][1024] bf16 row-major (K contig), B = wb [1024][1024] (K contig)
// 128x128 tile, 4 waves, each wave 64x64 via 4x4 16x16x32 frags, BK=32.
__global__ __launch_bounds__(256) void gemm_kernel(const unsigned short* __restrict__ xb,
                                                   const unsigned short* __restrict__ wb,
                                                   unsigned short* __restrict__ gb) {
  __shared__ __attribute__((aligned(16))) unsigned short As[128 * 32];
  __shared__ __attribute__((aligned(16))) unsigned short Bs[128 * 32];
  const int tid = threadIdx.x;
  const int bn = blockIdx.x & 7, bm = blockIdx.x >> 3;
  const int lane = tid & 63, w = tid >> 6;
  const int wm = (w & 1) * 64, wn = (w >> 1) * 64;
  const int q = lane >> 4, li = lane & 15;
  const int c0 = tid, c1 = tid + 256;

  f32x4 acc[4][4] = {};
  const unsigned short* Abase = xb + (size_t)bm * 128 * DDIM;
  const unsigned short* Bbase = wb + (size_t)bn * 128 * DDIM;

  for (int kt = 0; kt < 32; ++kt) {
    const int k0 = kt * 32;
    // stage 128x32 A and B tiles; chunk c: row=c>>2, 16B sub=c&3 (LDS linear = load order)
    load_lds16(Abase + (size_t)(c0 >> 2) * DDIM + k0 + (c0 & 3) * 8, &As[c0 * 8]);
    load_lds16(Abase + (size_t)(c1 >> 2) * DDIM + k0 + (c1 & 3) * 8, &As[c1 * 8]);
    load_lds16(Bbase + (size_t)(c0 >> 2) * DDIM + k0 + (c0 & 3) * 8, &Bs[c0 * 8]);
    load_lds16(Bbase + (size_t)(c1 >> 2) * DDIM + k0 + (c1 & 3) * 8, &Bs[c1 * 8]);
    __syncthreads();

    bf16x8 af[4], bfr[4];
#pragma unroll
    for (int mi = 0; mi < 4; ++mi)
      af[mi] = *(const bf16x8*)&As[(wm + mi * 16 + li) * 32 + q * 8];
#pragma unroll
    for (int ni = 0; ni < 4; ++ni)
      bfr[ni] = *(const bf16x8*)&Bs[(wn + ni * 16 + li) * 32 + q * 8];
#pragma unroll
    for (int mi = 0; mi < 4; ++mi)
#pragma unroll
      for (int ni = 0; ni < 4; ++ni)
        acc[mi][ni] = __builtin_amdgcn_mfma_f32_16x16x32_bf16(af[mi], bfr[ni], acc[mi][ni], 0, 0, 0);
    __syncthreads();
  }
  // epilogue: C/D layout col=lane&15, row=(lane>>4)*4+reg
#pragma unroll
  for (int mi = 0; mi < 4; ++mi)
#pragma unroll
    for (int ni = 0; ni < 4; ++ni) {
      const int col = bn * 128 + wn + ni * 16 + li;
      const size_t row0 = (size_t)(bm * 128 + wm + mi * 16 + q * 4);
#pragma unroll
      for (int rr = 0; rr < 4; ++rr)
        gb[(row0 + rr) * NDIM + col] = f2bf(acc[mi][ni][rr]);
    }
}

// ---------------- si/sj: one wave per (bn,h) ----------------
__global__ __launch_bounds__(256) void sisj_kernel(const unsigned short* __restrict__ gb,
                                                   const float* __restrict__ attn_w,
                                                   float* __restrict__ si_ws,
                                                   float* __restrict__ sj_ws) {
  const int tid = threadIdx.x, lane = tid & 63, wv = tid >> 6;
  const int idx = blockIdx.x * 4 + wv;   // (bn, h)
  const int bn = idx >> 3, h = idx & 7;
  const unsigned v = *(const unsigned*)(gb + (size_t)bn * NDIM + h * CDIM + lane * 2);
  const float g0 = bf2f((unsigned short)v), g1 = bf2f((unsigned short)(v >> 16));
  const int c = lane * 2;
  float psj = g0 * attn_w[c] + g1 * attn_w[c + 1];          // wl = attn_w[:C]
  float psi = g0 * attn_w[CDIM + c] + g1 * attn_w[CDIM + c + 1];  // wr = attn_w[C:]
#pragma unroll
  for (int off = 32; off; off >>= 1) {
    psj += __shfl_down(psj, off);
    psi += __shfl_down(psi, off);
  }
  if (lane == 0) {
    const int b = bn / NB, n = bn % NB;
    const int o = (b * HEADS + h) * NB + n;
    si_ws[o] = psi;
    sj_ws[o] = psj;
  }
}

// ---------------- adjacency row bitmasks: rm[i][w], bit j ----------------
__global__ void rowmask_kernel(const float* __restrict__ adj, unsigned* __restrict__ rm) {
  const int i = threadIdx.x;
  if (i >= 144) return;
  unsigned w[6] = {0, 0, 0, 0, 0, 0};
  if (i < NB)
    for (int j = 0; j < NB; ++j)
      if (adj[i * NB + j] != 0.f) w[j >> 5] |= 1u << (j & 31);
#pragma unroll
  for (int k = 0; k < 6; ++k) rm[i * 6 + k] = w[k];
}

// ---------------- column softmax stats per (b,h): m[j], 1/denom[j] ----------------
__global__ __launch_bounds__(192) void stats_kernel(const float* __restrict__ adj,
                                                    const float* __restrict__ si_ws,
                                                    const float* __restrict__ sj_ws,
                                                    float* __restrict__ m_ws,
                                                    float* __restrict__ rd_ws) {
  __shared__ float siL[NB];
  const int tid = threadIdx.x;
  const int b = blockIdx.x >> 3, h = blockIdx.x & 7;
  const int base = (b * HEADS + h) * NB;
  if (tid < NB) siL[tid] = si_ws[base + tid];
  __syncthreads();
  if (tid >= NB) return;
  const float sj = sj_ws[base + tid];
  float m = -3.0e38f;
  for (int i = 0; i < NB; ++i) {
    if (adj[i * NB + tid] != 0.f) {
      float e = siL[i] + sj;
      e = (e > 0.f) ? e : 0.2f * e;
      m = fmaxf(m, e);
    }
  }
  float s = 0.f;
  for (int i = 0; i < NB; ++i) {
    if (adj[i * NB + tid] != 0.f) {
      float e = siL[i] + sj;
      e = (e > 0.f) ? e : 0.2f * e;
      s += __expf(e - m);
    }
  }
  m_ws[base + tid] = m;
  rd_ws[base + tid] = 1.0f / s;
}

// ---------------- aggregation: out[b,i,h,:] = sum_j a[i,j] * g[b,j,h,:] ----------------
// Block per (b,h). A-frag (attention weights) computed in registers; g^T staged in LDS.
__global__ __launch_bounds__(256) void agg_kernel(const unsigned short* __restrict__ gb,
                                                  const float* __restrict__ si_ws,
                                                  const float* __restrict__ sj_ws,
                                                  const float* __restrict__ m_ws,
                                                  const float* __restrict__ rd_ws,
                                                  const unsigned* __restrict__ rm_ws,
                                                  float* __restrict__ out) {
  __shared__ __attribute__((aligned(16))) unsigned short gT[128 * 168]; // [f][j], stride 168 (2-way only)
  __shared__ __attribute__((aligned(16))) float4 smr[160];              // (sj, m, rd, 0) per j
  __shared__ float siL[144];
  __shared__ unsigned rmL[144 * 6];
  const int tid = threadIdx.x;
  const int b = blockIdx.x >> 3, h = blockIdx.x & 7;
  const int base = (b * HEADS + h) * NB;

  // zero gT (cols >=133 must be 0; LDS is uninitialized)
  unsigned* z = (unsigned*)gT;
  for (int k = tid; k < 128 * 168 / 2; k += 256) z[k] = 0;
  for (int j = tid; j < 160; j += 256) {
    float4 v = {0.f, 0.f, 0.f, 0.f};
    if (j < NB) { v.x = sj_ws[base + j]; v.y = m_ws[base + j]; v.z = rd_ws[base + j]; }
    smr[j] = v;
  }
  for (int i = tid; i < 144; i += 256) siL[i] = (i < NB) ? si_ws[base + i] : 0.f;
  for (int k = tid; k < 144 * 6; k += 256) rmL[k] = rm_ws[k];
  __syncthreads();

  // stage g_h transposed: gT[f][j] = g[b,j,h,f]
  const unsigned short* gsrc = gb + (size_t)b * NB * NDIM + h * CDIM;
  for (int t = tid; t < NB * 64; t += 256) {
    const int j = t >> 6, fp = t & 63;
    const unsigned v = *(const unsigned*)(gsrc + (size_t)j * NDIM + fp * 2);
    gT[(fp * 2) * 168 + j]     = (unsigned short)v;
    gT[(fp * 2 + 1) * 168 + j] = (unsigned short)(v >> 16);
  }
  __syncthreads();

  const int lane = tid & 63, wv = tid >> 6, q = lane >> 4, li = lane & 15;
  for (int mt = wv; mt < 9; mt += 4) {          // 9 m-tiles of 16 rows
    const int i_l = mt * 16 + li;
    const float si_r = siL[i_l];
    const unsigned* rmrow = &rmL[i_l * 6];
    f32x4 acc[8] = {};
#pragma unroll
    for (int ks = 0; ks < 5; ++ks) {            // K = 160 (j padded, masked to 0)
      const int j0 = ks * 32 + q * 8;
      const unsigned bits = rmrow[j0 >> 5] >> (j0 & 31);
      union { unsigned short s[8]; bf16x8 v; } af;
#pragma unroll
      for (int jj = 0; jj < 8; ++jj) {
        const float4 sv = smr[j0 + jj];
        float e = si_r + sv.x;
        e = (e > 0.f) ? e : 0.2f * e;
        const float wgt = ((bits >> jj) & 1u) ? __expf(e - sv.y) * sv.z : 0.f;
        af.s[jj] = f2bf(wgt);
      }
#pragma unroll
      for (int n = 0; n < 8; ++n) {
        const bf16x8 bv = *(const bf16x8*)&gT[(n * 16 + li) * 168 + j0];
        acc[n] = __builtin_amdgcn_mfma_f32_16x16x32_bf16(af.v, bv, acc[n], 0, 0, 0);
      }
    }
#pragma unroll
    for (int n = 0; n < 8; ++n)
#pragma unroll
      for (int rr = 0; rr < 4; ++rr) {
        const int i = mt * 16 + q * 4 + rr;
        if (i < NB)
          out[((size_t)(b * NB + i)) * NDIM + h * CDIM + n * 16 + li] = acc[n][rr];
      }
  }
}

extern "C" void kernel_launch(void* const* d_in, const int* in_sizes, int n_in,
                              void* d_out, int out_size, void* d_ws, size_t ws_size,
                              hipStream_t stream) {
  const float* x      = (const float*)d_in[0];
  const float* W      = (const float*)d_in[1];
  const float* attn_w = (const float*)d_in[2];
  const float* adj    = (const float*)d_in[3];
  float* out = (float*)d_out;
  char* ws = (char*)d_ws;

  // workspace layout (bytes), ~146 MB total
  unsigned short* xb = (unsigned short*)(ws + 0);          // 69,730,304
  unsigned short* wb = (unsigned short*)(ws + 69730304);   //  2,097,152
  unsigned short* gb = (unsigned short*)(ws + 71827456);   // 69,730,304
  float* si = (float*)(ws + 141557760);                    //  1,089,536  [b][h][n]
  float* sj = (float*)(ws + 142647296);
  float* mm = (float*)(ws + 143736832);
  float* rd = (float*)(ws + 144826368);
  unsigned* rm = (unsigned*)(ws + 145915904);              //      3,456

  cvt_kernel<<<(MROWS * DDIM / 8 + 255) / 256, 256, 0, stream>>>(x, xb, MROWS * DDIM / 8);
  cvt_kernel<<<(NDIM * DDIM / 8 + 255) / 256, 256, 0, stream>>>(W, wb, NDIM * DDIM / 8);
  rowmask_kernel<<<1, 256, 0, stream>>>(adj, rm);
  gemm_kernel<<<266 * 8, 256, 0, stream>>>(xb, wb, gb);
  sisj_kernel<<<MROWS * HEADS / 4, 256, 0, stream>>>(gb, attn_w, si, sj);
  stats_kernel<<<BATCH * HEADS, 192, 0, stream>>>(adj, si, sj, mm, rd);
  agg_kernel<<<BATCH * HEADS, 256, 0, stream>>>(gb, si, sj, mm, rd, rm, out);
}